// Round 1
// baseline (2862.277 us; speedup 1.0000x reference)
//
#include <hip/hip_runtime.h>

#define HH 128
#define WW 256
#define CH 64
#define HWP (HH * WW)   // 32768

// ---------------------------------------------------------------------------
// conv3x3 (pad=1, no bias) with optional fused leaky-relu(0.1) and residual add
// in, res, out: (B, 64, H, W) NCHW.  wt: (64, 64, 3, 3) OIHW.
// grid: (W/16, H/16, B), block: 256 (16x16). Each thread: 1 pixel, all 64 c_out.
// ---------------------------------------------------------------------------
__global__ __launch_bounds__(256) void conv3x3_k(
    const float* __restrict__ in, const float* __restrict__ wt,
    const float* __restrict__ res, float* __restrict__ out, int lrelu)
{
    __shared__ float tile[8][18][18];
    const int tid = threadIdx.x;
    const int tx = tid & 15, ty = tid >> 4;
    const int x0 = blockIdx.x * 16, y0 = blockIdx.y * 16;
    const int b = blockIdx.z;
    const float* inb = in + (size_t)b * CH * HWP;

    float acc[64];
#pragma unroll
    for (int i = 0; i < 64; ++i) acc[i] = 0.f;

    for (int cc = 0; cc < 8; ++cc) {
        __syncthreads();
        // stage 8 input channels of an 18x18 halo tile
        for (int idx = tid; idx < 8 * 324; idx += 256) {
            int cil = idx / 324;
            int r   = idx - cil * 324;
            int yy  = r / 18, xx = r - yy * 18;
            int gy = y0 + yy - 1, gx = x0 + xx - 1;
            float v = 0.f;
            if ((unsigned)gy < HH && (unsigned)gx < WW)
                v = inb[((size_t)(cc * 8 + cil) * HH + gy) * WW + gx];
            tile[cil][yy][xx] = v;
        }
        __syncthreads();
        for (int cil = 0; cil < 8; ++cil) {
            const int ci = cc * 8 + cil;
            float v[9];
#pragma unroll
            for (int dy = 0; dy < 3; ++dy)
#pragma unroll
                for (int dx = 0; dx < 3; ++dx)
                    v[dy * 3 + dx] = tile[cil][ty + dy][tx + dx];
            const float* wp = wt + (size_t)ci * 9;   // + co*576
#pragma unroll
            for (int co = 0; co < 64; ++co) {
                const float* w9 = wp + (size_t)co * 576;
                float a = acc[co];
                a = fmaf(w9[0], v[0], a);
                a = fmaf(w9[1], v[1], a);
                a = fmaf(w9[2], v[2], a);
                a = fmaf(w9[3], v[3], a);
                a = fmaf(w9[4], v[4], a);
                a = fmaf(w9[5], v[5], a);
                a = fmaf(w9[6], v[6], a);
                a = fmaf(w9[7], v[7], a);
                a = fmaf(w9[8], v[8], a);
                acc[co] = a;
            }
        }
    }

    const int y = y0 + ty, x = x0 + tx;
    const size_t pbase = (size_t)b * CH * HWP + (size_t)y * WW + x;
#pragma unroll
    for (int co = 0; co < 64; ++co) {
        float a = acc[co];
        if (lrelu) a = (a > 0.f) ? a : 0.1f * a;
        if (res)   a += res[pbase + (size_t)co * HWP];
        out[pbase + (size_t)co * HWP] = a;
    }
}

// ---------------------------------------------------------------------------
// 1x1 conv with bias, NCHW input -> transposed (B, HW, C) output.
// grid: 256 blocks x 256 threads, thread = 1 pixel (over B*HW).
// ---------------------------------------------------------------------------
__global__ __launch_bounds__(256) void conv1x1T_k(
    const float* __restrict__ in, const float* __restrict__ wt,
    const float* __restrict__ bias, float* __restrict__ outT)
{
    const size_t gp = (size_t)blockIdx.x * 256 + threadIdx.x;  // 0..65535
    const int    b  = (int)(gp >> 15);
    const size_t p  = gp & (size_t)(HWP - 1);
    const float* inb = in + (size_t)b * CH * HWP + p;

    float acc[64];
#pragma unroll
    for (int co = 0; co < 64; ++co) acc[co] = bias[co];

    for (int c4 = 0; c4 < 16; ++c4) {
        float v0 = inb[(size_t)(c4 * 4 + 0) * HWP];
        float v1 = inb[(size_t)(c4 * 4 + 1) * HWP];
        float v2 = inb[(size_t)(c4 * 4 + 2) * HWP];
        float v3 = inb[(size_t)(c4 * 4 + 3) * HWP];
#pragma unroll
        for (int co = 0; co < 64; ++co) {
            const float* w4 = wt + co * 64 + c4 * 4;
            acc[co] = fmaf(w4[0], v0, fmaf(w4[1], v1,
                      fmaf(w4[2], v2, fmaf(w4[3], v3, acc[co]))));
        }
    }
    float* op = outT + gp * 64;
#pragma unroll
    for (int i = 0; i < 16; ++i)
        ((float4*)op)[i] = make_float4(acc[4*i], acc[4*i+1], acc[4*i+2], acc[4*i+3]);
}

// ---------------------------------------------------------------------------
// Attention: one wave per pixel, lane = channel.
// QT/ST/RT: (B, HW, 64).  Writes bufT (B,HW,64) and M (B,HW,16).
// grid: 16384 blocks x 256 (4 waves/block).
// ---------------------------------------------------------------------------
__global__ __launch_bounds__(256) void attn_k(
    const float* __restrict__ QT, const float* __restrict__ ST,
    const float* __restrict__ RT, const int* __restrict__ xxs,
    const int* __restrict__ yys, float* __restrict__ bufT,
    float* __restrict__ Mout)
{
    const int lane = threadIdx.x & 63;
    const size_t gp = (size_t)blockIdx.x * 4 + (threadIdx.x >> 6);  // over B*HW
    const size_t bbase = (gp >> 15) << 15;

    const float q = QT[gp * 64 + lane];
    const int* xp = xxs + gp * 16;
    const int* yp = yys + gp * 16;
    int idx[16];
#pragma unroll
    for (int k = 0; k < 16; ++k) idx[k] = xp[k] * WW + yp[k];

    float sc[16];
#pragma unroll
    for (int k = 0; k < 16; ++k) {
        float s = ST[(bbase + (size_t)idx[k]) * 64 + lane] * q;
#pragma unroll
        for (int m = 32; m >= 1; m >>= 1) s += __shfl_xor(s, m, 64);
        sc[k] = s;
    }
    float mx = sc[0];
#pragma unroll
    for (int k = 1; k < 16; ++k) mx = fmaxf(mx, sc[k]);
    float e[16];
    float sum = 0.f;
#pragma unroll
    for (int k = 0; k < 16; ++k) { e[k] = __expf(sc[k] - mx); sum += e[k]; }
    const float inv = 1.f / sum;

    float acc = 0.f;
#pragma unroll
    for (int k = 0; k < 16; ++k) {
        const float m = e[k] * inv;
        acc = fmaf(m, RT[(bbase + (size_t)idx[k]) * 64 + lane], acc);
        e[k] = m;
    }
    bufT[gp * 64 + lane] = acc;
    if (lane == 0) {
#pragma unroll
        for (int k = 0; k < 16; ++k) Mout[gp * 16 + k] = e[k];
    }
}

// ---------------------------------------------------------------------------
// Fusion 1x1 conv: out[b,co,p] = bias[co] + W[co,0:64]·bufT[p,:] + W[co,64:128]·x_left[b,:,p]
// wt: (64,128). out: (B,64,H,W) NCHW.
// ---------------------------------------------------------------------------
__global__ __launch_bounds__(256) void fuse_k(
    const float* __restrict__ bufT, const float* __restrict__ xl,
    const float* __restrict__ wt, const float* __restrict__ bias,
    float* __restrict__ out)
{
    const size_t gp = (size_t)blockIdx.x * 256 + threadIdx.x;
    const int    b  = (int)(gp >> 15);
    const size_t p  = gp & (size_t)(HWP - 1);

    float acc[64];
#pragma unroll
    for (int co = 0; co < 64; ++co) acc[co] = bias[co];

    const float4* bp = (const float4*)(bufT + gp * 64);
    for (int c4 = 0; c4 < 16; ++c4) {
        float4 v = bp[c4];
#pragma unroll
        for (int co = 0; co < 64; ++co) {
            const float* w4 = wt + co * 128 + c4 * 4;
            acc[co] = fmaf(w4[0], v.x, fmaf(w4[1], v.y,
                      fmaf(w4[2], v.z, fmaf(w4[3], v.w, acc[co]))));
        }
    }
    const float* xlb = xl + (size_t)b * CH * HWP + p;
    for (int c4 = 0; c4 < 16; ++c4) {
        float v0 = xlb[(size_t)(c4 * 4 + 0) * HWP];
        float v1 = xlb[(size_t)(c4 * 4 + 1) * HWP];
        float v2 = xlb[(size_t)(c4 * 4 + 2) * HWP];
        float v3 = xlb[(size_t)(c4 * 4 + 3) * HWP];
#pragma unroll
        for (int co = 0; co < 64; ++co) {
            const float* w4 = wt + co * 128 + 64 + c4 * 4;
            acc[co] = fmaf(w4[0], v0, fmaf(w4[1], v1,
                      fmaf(w4[2], v2, fmaf(w4[3], v3, acc[co]))));
        }
    }
    float* op = out + (size_t)b * CH * HWP + p;
#pragma unroll
    for (int co = 0; co < 64; ++co) op[(size_t)co * HWP] = acc[co];
}

// ---------------------------------------------------------------------------
extern "C" void kernel_launch(void* const* d_in, const int* in_sizes, int n_in,
                              void* d_out, int out_size, void* d_ws, size_t ws_size,
                              hipStream_t stream)
{
    const float* x_left  = (const float*)d_in[0];
    const float* x_right = (const float*)d_in[1];
    const int*   xxs     = (const int*)d_in[2];
    const int*   yys     = (const int*)d_in[3];
    // d_in[4] = is_training (0) — tuple output path
    const float* rb_w1   = (const float*)d_in[5];
    const float* rb_w2   = (const float*)d_in[6];
    const float* b1_w    = (const float*)d_in[7];
    const float* b1_b    = (const float*)d_in[8];
    const float* b2_w    = (const float*)d_in[9];
    const float* b2_b    = (const float*)d_in[10];
    const float* b3_w    = (const float*)d_in[11];
    const float* b3_b    = (const float*)d_in[12];
    const float* fus_w   = (const float*)d_in[13];
    const float* fus_b   = (const float*)d_in[14];

    float* out  = (float*)d_out;                 // (2,64,128,256)
    float* Mout = out + (size_t)2 * CH * HWP;    // (2,32768,1,16)

    const size_t NB = (size_t)2 * CH * HWP;      // 4,194,304 floats per buffer
    float* ws = (float*)d_ws;
    float* W0 = ws;
    float* W1 = ws + NB;
    float* W2 = ws + 2 * NB;
    float* W3 = ws + 3 * NB;

    dim3 cgrid(WW / 16, HH / 16, 2), cblk(256);

    // residual blocks (shared weights)
    conv3x3_k<<<cgrid, cblk, 0, stream>>>(x_left,  rb_w1, nullptr, W2, 1);
    conv3x3_k<<<cgrid, cblk, 0, stream>>>(W2,      rb_w2, x_left,  W0, 0);  // buf_l
    conv3x3_k<<<cgrid, cblk, 0, stream>>>(x_right, rb_w1, nullptr, W2, 1);
    conv3x3_k<<<cgrid, cblk, 0, stream>>>(W2,      rb_w2, x_right, W1, 0);  // buf_r

    // 1x1 projections -> transposed (B,HW,C)
    conv1x1T_k<<<256, 256, 0, stream>>>(W0, b1_w, b1_b, W2);  // QT
    conv1x1T_k<<<256, 256, 0, stream>>>(W1, b2_w, b2_b, W3);  // ST
    conv1x1T_k<<<256, 256, 0, stream>>>(W1, b3_w, b3_b, W0);  // RT (buf_r dead after this)

    // attention: QT=W2, ST=W3, RT=W0 -> bufT=W1, M
    attn_k<<<16384, 256, 0, stream>>>(W2, W3, W0, xxs, yys, W1, Mout);

    // fusion conv
    fuse_k<<<256, 256, 0, stream>>>(W1, x_left, fus_w, fus_b, out);
}

// Round 2
// 537.593 us; speedup vs baseline: 5.3242x; 5.3242x over previous
//
#include <hip/hip_runtime.h>

#define HH 128
#define WW 256
#define CH 64
#define HWP (HH * WW)   // 32768

typedef __attribute__((ext_vector_type(8))) __bf16 bf16x8;
typedef __attribute__((ext_vector_type(16))) float float16;

__device__ __forceinline__ unsigned short f2bf(float f) {
    unsigned u = __float_as_uint(f);
    u += 0x7fffu + ((u >> 16) & 1u);     // RNE
    return (unsigned short)(u >> 16);
}

// ---------------------------------------------------------------------------
// Weight prep: OIHW fp32 (64,64,3,3) -> bf16 B-fragment layout for
// mfma_f32_32x32x16_bf16.  k = (dy*3+dx)*64 + ci, chunked kc=k/16.
// wB[conv][ ((kc*2+nb)*64 + lane)*8 + j ] = w[n=nb*32+(lane&31)][ci][kd],
// where k = kc*16 + (lane>>5)*8 + j.  36864 elems per conv.
// ---------------------------------------------------------------------------
__global__ __launch_bounds__(256) void prep_w_k(
    const float* __restrict__ w1, const float* __restrict__ w2,
    unsigned short* __restrict__ wB)
{
    int e = blockIdx.x * 256 + threadIdx.x;         // 0..73727
    const float* w = (e < 36864) ? w1 : w2;
    int t = (e < 36864) ? e : e - 36864;
    int j = t & 7, L = (t >> 3) & 63, nb = (t >> 9) & 1, kc = t >> 10;
    int k  = kc * 16 + (L >> 5) * 8 + j;
    int n  = nb * 32 + (L & 31);
    int kd = k >> 6, ci = k & 63;
    wB[e] = f2bf(w[(n * 64 + ci) * 9 + kd]);
}

// ---------------------------------------------------------------------------
// conv3x3 via MFMA implicit GEMM.  grid (W/64, H, B), 256 thr = 4 waves.
// Block tile: 64 px (one row strip) x 64 c_out.  Wave: 32px x 32co quadrant.
// ---------------------------------------------------------------------------
__global__ __launch_bounds__(256) void conv3x3_mfma_k(
    const float* __restrict__ in, const unsigned short* __restrict__ wB,
    const float* __restrict__ res, float* __restrict__ out, int lrelu)
{
    __shared__ __align__(16) unsigned short sA[3 * 66 * 72];  // [row][col][ci] pad 72

    const int tid = threadIdx.x;
    const int x0  = blockIdx.x * 64;
    const int y   = blockIdx.y;
    const int b   = blockIdx.z;
    const float* inb = in + (size_t)b * CH * HWP;

    // stage halo: 3 rows x 66 cols x 64 ci, f32 -> bf16
    for (int i = tid; i < 3 * 66 * 64; i += 256) {
        int seg = i / 66;                 // row*64 + ci
        int col = i - seg * 66;
        int row = seg >> 6;
        int ci  = seg & 63;
        int gy = y + row - 1, gx = x0 + col - 1;
        float v = 0.f;
        if ((unsigned)gy < HH && (unsigned)gx < WW)
            v = inb[((size_t)ci * HH + gy) * WW + gx];
        sA[(row * 66 + col) * 72 + ci] = f2bf(v);
    }
    __syncthreads();

    const int lane = tid & 63;
    const int wv   = tid >> 6;
    const int mw   = wv & 1, nw = wv >> 1;
    const int m    = lane & 31, kg = lane >> 5;
    const int px_l = mw * 32 + m;

    float16 acc;
#pragma unroll
    for (int i = 0; i < 16; ++i) acc[i] = 0.f;

#pragma unroll
    for (int kc = 0; kc < 36; ++kc) {
        const int kd = kc >> 2, h = kc & 3;
        const int dy = kd / 3, dx = kd - dy * 3;
        const int ci0 = h * 16 + kg * 8;
        bf16x8 af = *(const bf16x8*)&sA[((dy * 66 + px_l + dx) * 72) + ci0];
        bf16x8 bfg = *(const bf16x8*)&wB[((kc * 2 + nw) * 64 + lane) * 8];
        acc = __builtin_amdgcn_mfma_f32_32x32x16_bf16(af, bfg, acc, 0, 0, 0);
    }

    // transpose through LDS for coalesced NCHW stores
    __syncthreads();
    float* obuf = (float*)sA;            // [co][px] pad 68  (17.4KB <= 28.5KB)
    const int co_l = nw * 32 + (lane & 31);
#pragma unroll
    for (int r = 0; r < 16; ++r) {
        int pr = mw * 32 + (r & 3) + 8 * (r >> 2) + 4 * kg;
        obuf[co_l * 68 + pr] = acc[r];
    }
    __syncthreads();

    const int co = tid >> 2;
    const int p0 = (tid & 3) * 16;
    const size_t gbase = ((size_t)b * CH + co) * HWP + (size_t)y * WW + x0 + p0;
#pragma unroll
    for (int q = 0; q < 4; ++q) {
        float4 v = *(float4*)&obuf[co * 68 + p0 + q * 4];
        if (lrelu) {
            v.x = v.x > 0.f ? v.x : 0.1f * v.x;
            v.y = v.y > 0.f ? v.y : 0.1f * v.y;
            v.z = v.z > 0.f ? v.z : 0.1f * v.z;
            v.w = v.w > 0.f ? v.w : 0.1f * v.w;
        }
        if (res) {
            float4 rv = *(const float4*)&res[gbase + q * 4];
            v.x += rv.x; v.y += rv.y; v.z += rv.z; v.w += rv.w;
        }
        *(float4*)&out[gbase + q * 4] = v;
    }
}

// ---------------------------------------------------------------------------
// 1x1 conv with bias, NCHW -> transposed (B,HW,C).  grid 1024 x 256.
// Thread: 16 c_out of one pixel (lane = pixel -> coalesced input reads).
// ---------------------------------------------------------------------------
__global__ __launch_bounds__(256) void conv1x1T_k(
    const float* __restrict__ in, const float* __restrict__ wt,
    const float* __restrict__ bias, float* __restrict__ outT)
{
    const int t  = threadIdx.x;
    const int px = t & 63, cg = t >> 6;
    const size_t gp = (size_t)blockIdx.x * 64 + px;
    const int    b  = (int)(gp >> 15);
    const size_t p  = gp & (size_t)(HWP - 1);
    const float* inb = in + (size_t)b * CH * HWP + p;

    float acc[16];
#pragma unroll
    for (int i = 0; i < 16; ++i) acc[i] = bias[cg * 16 + i];

    for (int ci = 0; ci < 64; ++ci) {
        float v = inb[(size_t)ci * HWP];
        const float* wp = wt + (cg * 16) * 64 + ci;
#pragma unroll
        for (int i = 0; i < 16; ++i) acc[i] = fmaf(wp[i * 64], v, acc[i]);
    }
    float* op = outT + gp * 64 + cg * 16;
#pragma unroll
    for (int q = 0; q < 4; ++q)
        *(float4*)&op[q * 4] = make_float4(acc[q*4], acc[q*4+1], acc[q*4+2], acc[q*4+3]);
}

// ---------------------------------------------------------------------------
// Attention: one wave per pixel, lane = channel.
// ---------------------------------------------------------------------------
__global__ __launch_bounds__(256) void attn_k(
    const float* __restrict__ QT, const float* __restrict__ ST,
    const float* __restrict__ RT, const int* __restrict__ xxs,
    const int* __restrict__ yys, float* __restrict__ bufT,
    float* __restrict__ Mout)
{
    const int lane = threadIdx.x & 63;
    const size_t gp = (size_t)blockIdx.x * 4 + (threadIdx.x >> 6);
    const size_t bbase = (gp >> 15) << 15;

    const float q = QT[gp * 64 + lane];
    const int* xp = xxs + gp * 16;
    const int* yp = yys + gp * 16;
    int idx[16];
#pragma unroll
    for (int k = 0; k < 16; ++k) idx[k] = xp[k] * WW + yp[k];

    float sc[16];
#pragma unroll
    for (int k = 0; k < 16; ++k) {
        float s = ST[(bbase + (size_t)idx[k]) * 64 + lane] * q;
#pragma unroll
        for (int m = 32; m >= 1; m >>= 1) s += __shfl_xor(s, m, 64);
        sc[k] = s;
    }
    float mx = sc[0];
#pragma unroll
    for (int k = 1; k < 16; ++k) mx = fmaxf(mx, sc[k]);
    float e[16];
    float sum = 0.f;
#pragma unroll
    for (int k = 0; k < 16; ++k) { e[k] = __expf(sc[k] - mx); sum += e[k]; }
    const float inv = 1.f / sum;

    float acc = 0.f;
#pragma unroll
    for (int k = 0; k < 16; ++k) {
        const float m = e[k] * inv;
        acc = fmaf(m, RT[(bbase + (size_t)idx[k]) * 64 + lane], acc);
        e[k] = m;
    }
    bufT[gp * 64 + lane] = acc;
    if (lane == 0) {
#pragma unroll
        for (int k = 0; k < 16; ++k) Mout[gp * 16 + k] = e[k];
    }
}

// ---------------------------------------------------------------------------
// Fusion 1x1 (128 -> 64), NCHW out.  grid 1024 x 256, thread = 16 co of 1 px.
// ---------------------------------------------------------------------------
__global__ __launch_bounds__(256) void fuse_k(
    const float* __restrict__ bufT, const float* __restrict__ xl,
    const float* __restrict__ wt, const float* __restrict__ bias,
    float* __restrict__ out)
{
    const int t  = threadIdx.x;
    const int px = t & 63, cg = t >> 6;
    const size_t gp = (size_t)blockIdx.x * 64 + px;
    const int    b  = (int)(gp >> 15);
    const size_t p  = gp & (size_t)(HWP - 1);

    float acc[16];
#pragma unroll
    for (int i = 0; i < 16; ++i) acc[i] = bias[cg * 16 + i];

    const float* bp = bufT + gp * 64;
    for (int ci = 0; ci < 64; ++ci) {
        float v = bp[ci];
        const float* wp = wt + (cg * 16) * 128 + ci;
#pragma unroll
        for (int i = 0; i < 16; ++i) acc[i] = fmaf(wp[i * 128], v, acc[i]);
    }
    const float* xlb = xl + (size_t)b * CH * HWP + p;
    for (int ci = 0; ci < 64; ++ci) {
        float v = xlb[(size_t)ci * HWP];
        const float* wp = wt + (cg * 16) * 128 + 64 + ci;
#pragma unroll
        for (int i = 0; i < 16; ++i) acc[i] = fmaf(wp[i * 128], v, acc[i]);
    }
    float* op = out + (size_t)b * CH * HWP + p;
#pragma unroll
    for (int i = 0; i < 16; ++i) op[(size_t)(cg * 16 + i) * HWP] = acc[i];
}

// ---------------------------------------------------------------------------
extern "C" void kernel_launch(void* const* d_in, const int* in_sizes, int n_in,
                              void* d_out, int out_size, void* d_ws, size_t ws_size,
                              hipStream_t stream)
{
    const float* x_left  = (const float*)d_in[0];
    const float* x_right = (const float*)d_in[1];
    const int*   xxs     = (const int*)d_in[2];
    const int*   yys     = (const int*)d_in[3];
    const float* rb_w1   = (const float*)d_in[5];
    const float* rb_w2   = (const float*)d_in[6];
    const float* b1_w    = (const float*)d_in[7];
    const float* b1_b    = (const float*)d_in[8];
    const float* b2_w    = (const float*)d_in[9];
    const float* b2_b    = (const float*)d_in[10];
    const float* b3_w    = (const float*)d_in[11];
    const float* b3_b    = (const float*)d_in[12];
    const float* fus_w   = (const float*)d_in[13];
    const float* fus_b   = (const float*)d_in[14];

    float* out  = (float*)d_out;                 // (2,64,128,256)
    float* Mout = out + (size_t)2 * CH * HWP;    // (2,32768,1,16)

    const size_t NB = (size_t)2 * CH * HWP;      // floats per (B,C,H,W) buffer
    float* ws = (float*)d_ws;
    float* W0 = ws;
    float* W1 = ws + NB;
    float* W2 = ws + 2 * NB;
    float* W3 = ws + 3 * NB;
    unsigned short* wB = (unsigned short*)(ws + 4 * NB);  // 2 x 36864 bf16

    // weight prep for the two 3x3 convs
    prep_w_k<<<288, 256, 0, stream>>>(rb_w1, rb_w2, wB);

    dim3 cgrid(WW / 64, HH, 2), cblk(256);
    const unsigned short* wB1 = wB;
    const unsigned short* wB2 = wB + 36864;

    // residual blocks (shared weights)
    conv3x3_mfma_k<<<cgrid, cblk, 0, stream>>>(x_left,  wB1, nullptr, W2, 1);
    conv3x3_mfma_k<<<cgrid, cblk, 0, stream>>>(W2,      wB2, x_left,  W0, 0);  // buf_l
    conv3x3_mfma_k<<<cgrid, cblk, 0, stream>>>(x_right, wB1, nullptr, W2, 1);
    conv3x3_mfma_k<<<cgrid, cblk, 0, stream>>>(W2,      wB2, x_right, W1, 0);  // buf_r

    // 1x1 projections -> transposed (B,HW,C)
    conv1x1T_k<<<1024, 256, 0, stream>>>(W0, b1_w, b1_b, W2);  // QT
    conv1x1T_k<<<1024, 256, 0, stream>>>(W1, b2_w, b2_b, W3);  // ST
    conv1x1T_k<<<1024, 256, 0, stream>>>(W1, b3_w, b3_b, W0);  // RT

    // attention: QT=W2, ST=W3, RT=W0 -> bufT=W1, M
    attn_k<<<16384, 256, 0, stream>>>(W2, W3, W0, xxs, yys, W1, Mout);

    // fusion conv
    fuse_k<<<1024, 256, 0, stream>>>(W1, x_left, fus_w, fus_b, out);
}

// Round 3
// 340.098 us; speedup vs baseline: 8.4160x; 1.5807x over previous
//
#include <hip/hip_runtime.h>

#define HH 128
#define WW 256
#define CH 64
#define HWP (HH * WW)   // 32768

typedef __attribute__((ext_vector_type(8))) __bf16 bf16x8;
typedef __attribute__((ext_vector_type(16))) float float16;

__device__ __forceinline__ unsigned short f2bf(float f) {
    unsigned u = __float_as_uint(f);
    u += 0x7fffu + ((u >> 16) & 1u);     // RNE
    return (unsigned short)(u >> 16);
}

// ---------------------------------------------------------------------------
// Weight prep -> bf16 B-fragment layouts for mfma_f32_32x32x16_bf16.
// Fragment layout: frag[((kc*NT + nt)*64 + lane)*8 + j] = W[n][k],
//   n = nt*32 + (lane&31),  k = kc*16 + (lane>>5)*8 + j.
// Segments in wB:
//   [0,36864)        rb_w1 (K=576 with k=(dy*3+dx)*64+ci, NT=2)
//   [36864,73728)    rb_w2
//   [73728,77824)    b1_w   (K=64,  NT=2)
//   [77824,86016)    b2_w||b3_w (K=64, NT=4, n<64->b2, else b3)
//   [86016,94208)    fus_w  (K=128, NT=2)
// ---------------------------------------------------------------------------
__global__ __launch_bounds__(256) void prep_w_k(
    const float* __restrict__ w1, const float* __restrict__ w2,
    const float* __restrict__ b1w, const float* __restrict__ b2w,
    const float* __restrict__ b3w, const float* __restrict__ fusw,
    unsigned short* __restrict__ wB)
{
    int e = blockIdx.x * 256 + threadIdx.x;
    if (e >= 94208) return;
    float val;
    if (e < 73728) {
        const float* w = (e < 36864) ? w1 : w2;
        int t = (e < 36864) ? e : e - 36864;
        int j = t & 7, L = (t >> 3) & 63, nb = (t >> 9) & 1, kc = t >> 10;
        int k  = kc * 16 + (L >> 5) * 8 + j;
        int n  = nb * 32 + (L & 31);
        int kd = k >> 6, ci = k & 63;
        val = w[(n * 64 + ci) * 9 + kd];
    } else {
        int t = e - 73728;
        if (t < 4096) {                       // Q: K=64, NT=2
            int j = t & 7, L = (t >> 3) & 63, i3 = t >> 9;
            int nt = i3 & 1, kc = i3 >> 1;
            int n = nt * 32 + (L & 31), k = kc * 16 + (L >> 5) * 8 + j;
            val = b1w[n * 64 + k];
        } else if (t < 12288) {               // S||R: K=64, NT=4
            t -= 4096;
            int j = t & 7, L = (t >> 3) & 63, i3 = t >> 9;
            int nt = i3 & 3, kc = i3 >> 2;
            int n = nt * 32 + (L & 31), k = kc * 16 + (L >> 5) * 8 + j;
            val = (n < 64) ? b2w[n * 64 + k] : b3w[(n - 64) * 64 + k];
        } else {                              // FUS: K=128, NT=2
            t -= 12288;
            int j = t & 7, L = (t >> 3) & 63, i3 = t >> 9;
            int nt = i3 & 1, kc = i3 >> 1;
            int n = nt * 32 + (L & 31), k = kc * 16 + (L >> 5) * 8 + j;
            val = fusw[n * 128 + k];
        }
    }
    wB[e] = f2bf(val);
}

// ---------------------------------------------------------------------------
// conv3x3 via MFMA implicit GEMM (unchanged from round 2).
// ---------------------------------------------------------------------------
__global__ __launch_bounds__(256) void conv3x3_mfma_k(
    const float* __restrict__ in, const unsigned short* __restrict__ wB,
    const float* __restrict__ res, float* __restrict__ out, int lrelu)
{
    __shared__ __align__(16) unsigned short sA[3 * 66 * 72];

    const int tid = threadIdx.x;
    const int x0  = blockIdx.x * 64;
    const int y   = blockIdx.y;
    const int b   = blockIdx.z;
    const float* inb = in + (size_t)b * CH * HWP;

    for (int i = tid; i < 3 * 66 * 64; i += 256) {
        int seg = i / 66;
        int col = i - seg * 66;
        int row = seg >> 6;
        int ci  = seg & 63;
        int gy = y + row - 1, gx = x0 + col - 1;
        float v = 0.f;
        if ((unsigned)gy < HH && (unsigned)gx < WW)
            v = inb[((size_t)ci * HH + gy) * WW + gx];
        sA[(row * 66 + col) * 72 + ci] = f2bf(v);
    }
    __syncthreads();

    const int lane = tid & 63;
    const int wv   = tid >> 6;
    const int mw   = wv & 1, nw = wv >> 1;
    const int m    = lane & 31, kg = lane >> 5;
    const int px_l = mw * 32 + m;

    float16 acc;
#pragma unroll
    for (int i = 0; i < 16; ++i) acc[i] = 0.f;

#pragma unroll
    for (int kc = 0; kc < 36; ++kc) {
        const int kd = kc >> 2, h = kc & 3;
        const int dy = kd / 3, dx = kd - dy * 3;
        const int ci0 = h * 16 + kg * 8;
        bf16x8 af = *(const bf16x8*)&sA[((dy * 66 + px_l + dx) * 72) + ci0];
        bf16x8 bfg = *(const bf16x8*)&wB[((kc * 2 + nw) * 64 + lane) * 8];
        acc = __builtin_amdgcn_mfma_f32_32x32x16_bf16(af, bfg, acc, 0, 0, 0);
    }

    __syncthreads();
    float* obuf = (float*)sA;
    const int co_l = nw * 32 + (lane & 31);
#pragma unroll
    for (int r = 0; r < 16; ++r) {
        int pr = mw * 32 + (r & 3) + 8 * (r >> 2) + 4 * kg;
        obuf[co_l * 68 + pr] = acc[r];
    }
    __syncthreads();

    const int co = tid >> 2;
    const int p0 = (tid & 3) * 16;
    const size_t gbase = ((size_t)b * CH + co) * HWP + (size_t)y * WW + x0 + p0;
#pragma unroll
    for (int q = 0; q < 4; ++q) {
        float4 v = *(float4*)&obuf[co * 68 + p0 + q * 4];
        if (lrelu) {
            v.x = v.x > 0.f ? v.x : 0.1f * v.x;
            v.y = v.y > 0.f ? v.y : 0.1f * v.y;
            v.z = v.z > 0.f ? v.z : 0.1f * v.z;
            v.w = v.w > 0.f ? v.w : 0.1f * v.w;
        }
        if (res) {
            float4 rv = *(const float4*)&res[gbase + q * 4];
            v.x += rv.x; v.y += rv.y; v.z += rv.z; v.w += rv.w;
        }
        *(float4*)&out[gbase + q * 4] = v;
    }
}

// ---------------------------------------------------------------------------
// 1x1 conv via MFMA: NCHW f32 in -> T-layout f32 out (px-major 64ch rows).
// NT=2: N=64 -> out0.  NT=4: N=128 -> out0 (n<64) and out1 (n>=64).
// grid 1024 blocks x 256 thr; block = 64 px.
// ---------------------------------------------------------------------------
template<int NT>
__global__ __launch_bounds__(256) void lin_mfma_k(
    const float* __restrict__ X, const unsigned short* __restrict__ wfrag,
    const float* __restrict__ bias0, const float* __restrict__ bias1,
    float* __restrict__ out0, float* __restrict__ out1)
{
    constexpr int SC = NT * 32 + 4;                       // sC stride (dwords)
    constexpr int SMEM = (64 * SC * 4 > 64 * 72 * 2) ? 64 * SC * 4 : 64 * 72 * 2;
    __shared__ __align__(16) unsigned char smem[SMEM];
    unsigned short* sA = (unsigned short*)smem;           // [px][ci] stride 72
    float* sC = (float*)smem;                             // [px][n]  stride SC

    const int tid = threadIdx.x;
    const size_t gp0 = (size_t)blockIdx.x * 64;
    const int b    = (int)(gp0 >> 15);
    const int pofs = (int)(gp0 & (HWP - 1));
    const float* inb = X + (size_t)b * CH * HWP + pofs;

    for (int i = tid; i < 4096; i += 256) {
        int ci = i >> 6, px = i & 63;
        sA[px * 72 + ci] = f2bf(inb[(size_t)ci * HWP + px]);
    }
    __syncthreads();

    const int lane = tid & 63, wv = tid >> 6;
    const int mw = wv & 1, nw = wv >> 1;
    const int m = lane & 31, kg = lane >> 5;
    const int px_l = mw * 32 + m;

    float16 acc[NT / 2];
#pragma unroll
    for (int t = 0; t < NT / 2; ++t)
#pragma unroll
        for (int i = 0; i < 16; ++i) acc[t][i] = 0.f;

#pragma unroll
    for (int kc = 0; kc < 4; ++kc) {
        bf16x8 af = *(const bf16x8*)&sA[px_l * 72 + kc * 16 + kg * 8];
#pragma unroll
        for (int t = 0; t < NT / 2; ++t) {
            int nt = nw * (NT / 2) + t;
            bf16x8 bf = *(const bf16x8*)&wfrag[((kc * NT + nt) * 64 + lane) * 8];
            acc[t] = __builtin_amdgcn_mfma_f32_32x32x16_bf16(af, bf, acc[t], 0, 0, 0);
        }
    }
    __syncthreads();   // before smem reuse as sC

#pragma unroll
    for (int t = 0; t < NT / 2; ++t) {
        int nt = nw * (NT / 2) + t;
        int n = nt * 32 + (lane & 31);
        float bv = (NT == 2) ? bias0[n] : (n < 64 ? bias0[n] : bias1[n - 64]);
#pragma unroll
        for (int r = 0; r < 16; ++r) {
            int pr = mw * 32 + (r & 3) + 8 * (r >> 2) + 4 * kg;
            sC[pr * SC + n] = acc[t][r] + bv;
        }
    }
    __syncthreads();

    const int px = tid >> 2, c0 = (tid & 3) * 16;
    {
        float* op = out0 + (gp0 + px) * 64 + c0;
#pragma unroll
        for (int q = 0; q < 4; ++q)
            *(float4*)&op[q * 4] = *(float4*)&sC[px * SC + c0 + q * 4];
    }
    if (NT == 4) {
        float* op = out1 + (gp0 + px) * 64 + c0;
#pragma unroll
        for (int q = 0; q < 4; ++q)
            *(float4*)&op[q * 4] = *(float4*)&sC[px * SC + 64 + c0 + q * 4];
    }
}

// ---------------------------------------------------------------------------
// Attention: one wave per pixel, lane = channel.  bufT written as bf16.
// ---------------------------------------------------------------------------
__global__ __launch_bounds__(256) void attn_k(
    const float* __restrict__ QT, const float* __restrict__ ST,
    const float* __restrict__ RT, const int* __restrict__ xxs,
    const int* __restrict__ yys, unsigned short* __restrict__ bufT,
    float* __restrict__ Mout)
{
    const int lane = threadIdx.x & 63;
    const size_t gp = (size_t)blockIdx.x * 4 + (threadIdx.x >> 6);
    const size_t bbase = (gp >> 15) << 15;

    const float q = QT[gp * 64 + lane];
    const int* xp = xxs + gp * 16;
    const int* yp = yys + gp * 16;
    int idx[16];
#pragma unroll
    for (int k = 0; k < 16; ++k) idx[k] = xp[k] * WW + yp[k];

    float sc[16];
#pragma unroll
    for (int k = 0; k < 16; ++k) {
        float s = ST[(bbase + (size_t)idx[k]) * 64 + lane] * q;
#pragma unroll
        for (int m = 32; m >= 1; m >>= 1) s += __shfl_xor(s, m, 64);
        sc[k] = s;
    }
    float mx = sc[0];
#pragma unroll
    for (int k = 1; k < 16; ++k) mx = fmaxf(mx, sc[k]);
    float e[16];
    float sum = 0.f;
#pragma unroll
    for (int k = 0; k < 16; ++k) { e[k] = __expf(sc[k] - mx); sum += e[k]; }
    const float inv = 1.f / sum;

    float acc = 0.f;
#pragma unroll
    for (int k = 0; k < 16; ++k) {
        const float m = e[k] * inv;
        acc = fmaf(m, RT[(bbase + (size_t)idx[k]) * 64 + lane], acc);
        e[k] = m;
    }
    bufT[gp * 64 + lane] = f2bf(acc);
    if (lane == 0) {
#pragma unroll
        for (int k = 0; k < 16; ++k) Mout[gp * 16 + k] = e[k];
    }
}

// ---------------------------------------------------------------------------
// Fusion 1x1 via MFMA: K=128 (bufT bf16 rows + x_left NCHW), N=64, NCHW out.
// ---------------------------------------------------------------------------
__global__ __launch_bounds__(256) void fuse_mfma_k(
    const unsigned short* __restrict__ bufT, const float* __restrict__ xl,
    const unsigned short* __restrict__ wfrag, const float* __restrict__ bias,
    float* __restrict__ out)
{
    __shared__ __align__(16) unsigned char smem[64 * 136 * 2];  // == 64*68*4
    unsigned short* sA = (unsigned short*)smem;   // [px][k] stride 136 halves
    float* sC = (float*)smem;                     // [co][px] stride 68 dwords

    const int tid = threadIdx.x;
    const size_t gp0 = (size_t)blockIdx.x * 64;
    const int b    = (int)(gp0 >> 15);
    const int pofs = (int)(gp0 & (HWP - 1));

    // k 0..63: bufT rows (bf16, contiguous 128 B per px)
    for (int c = tid; c < 512; c += 256) {
        int px = c >> 3, off = (c & 7) * 8;
        uint4 v = *(const uint4*)&bufT[(gp0 + px) * 64 + off];
        *(uint4*)&sA[px * 136 + off] = v;
    }
    // k 64..127: x_left NCHW f32 -> bf16
    const float* xlb = xl + (size_t)b * CH * HWP + pofs;
    for (int i = tid; i < 4096; i += 256) {
        int ci = i >> 6, px = i & 63;
        sA[px * 136 + 64 + ci] = f2bf(xlb[(size_t)ci * HWP + px]);
    }
    __syncthreads();

    const int lane = tid & 63, wv = tid >> 6;
    const int mw = wv & 1, nw = wv >> 1;
    const int m = lane & 31, kg = lane >> 5;
    const int px_l = mw * 32 + m;

    float16 acc;
#pragma unroll
    for (int i = 0; i < 16; ++i) acc[i] = 0.f;

#pragma unroll
    for (int kc = 0; kc < 8; ++kc) {
        bf16x8 af = *(const bf16x8*)&sA[px_l * 136 + kc * 16 + kg * 8];
        bf16x8 bf = *(const bf16x8*)&wfrag[((kc * 2 + nw) * 64 + lane) * 8];
        acc = __builtin_amdgcn_mfma_f32_32x32x16_bf16(af, bf, acc, 0, 0, 0);
    }
    __syncthreads();

    const int co_l = nw * 32 + (lane & 31);
#pragma unroll
    for (int r = 0; r < 16; ++r) {
        int pr = mw * 32 + (r & 3) + 8 * (r >> 2) + 4 * kg;
        sC[co_l * 68 + pr] = acc[r];
    }
    __syncthreads();

    const int co = tid >> 2, p0 = (tid & 3) * 16;
    const float bv = bias[co];
    float* op = out + ((size_t)b * CH + co) * HWP + pofs + p0;
#pragma unroll
    for (int q = 0; q < 4; ++q) {
        float4 v = *(float4*)&sC[co * 68 + p0 + q * 4];
        v.x += bv; v.y += bv; v.z += bv; v.w += bv;
        *(float4*)&op[q * 4] = v;
    }
}

// ---------------------------------------------------------------------------
extern "C" void kernel_launch(void* const* d_in, const int* in_sizes, int n_in,
                              void* d_out, int out_size, void* d_ws, size_t ws_size,
                              hipStream_t stream)
{
    const float* x_left  = (const float*)d_in[0];
    const float* x_right = (const float*)d_in[1];
    const int*   xxs     = (const int*)d_in[2];
    const int*   yys     = (const int*)d_in[3];
    const float* rb_w1   = (const float*)d_in[5];
    const float* rb_w2   = (const float*)d_in[6];
    const float* b1_w    = (const float*)d_in[7];
    const float* b1_b    = (const float*)d_in[8];
    const float* b2_w    = (const float*)d_in[9];
    const float* b2_b    = (const float*)d_in[10];
    const float* b3_w    = (const float*)d_in[11];
    const float* b3_b    = (const float*)d_in[12];
    const float* fus_w   = (const float*)d_in[13];
    const float* fus_b   = (const float*)d_in[14];

    float* out  = (float*)d_out;                 // (2,64,128,256)
    float* Mout = out + (size_t)2 * CH * HWP;    // (2,32768,1,16)

    const size_t NB = (size_t)2 * CH * HWP;
    float* ws = (float*)d_ws;
    float* W0 = ws;
    float* W1 = ws + NB;
    float* W2 = ws + 2 * NB;
    float* W3 = ws + 3 * NB;
    unsigned short* wB = (unsigned short*)(ws + 4 * NB);  // 94208 bf16

    prep_w_k<<<368, 256, 0, stream>>>(rb_w1, rb_w2, b1_w, b2_w, b3_w, fus_w, wB);

    dim3 cgrid(WW / 64, HH, 2), cblk(256);
    // residual blocks (shared weights)
    conv3x3_mfma_k<<<cgrid, cblk, 0, stream>>>(x_left,  wB,         nullptr, W2, 1);
    conv3x3_mfma_k<<<cgrid, cblk, 0, stream>>>(W2,      wB + 36864, x_left,  W0, 0);  // buf_l
    conv3x3_mfma_k<<<cgrid, cblk, 0, stream>>>(x_right, wB,         nullptr, W2, 1);
    conv3x3_mfma_k<<<cgrid, cblk, 0, stream>>>(W2,      wB + 36864, x_right, W1, 0);  // buf_r

    // 1x1 projections -> T layout
    lin_mfma_k<2><<<1024, 256, 0, stream>>>(W0, wB + 73728, b1_b, nullptr, W2, nullptr);     // QT
    lin_mfma_k<4><<<1024, 256, 0, stream>>>(W1, wB + 77824, b2_b, b3_b,    W3, W0);          // ST, RT

    // attention: QT=W2, ST=W3, RT=W0 -> bufT bf16 in W1, M
    attn_k<<<16384, 256, 0, stream>>>(W2, W3, W0, xxs, yys, (unsigned short*)W1, Mout);

    // fusion conv
    fuse_mfma_k<<<1024, 256, 0, stream>>>((unsigned short*)W1, x_left, wB + 86016, fus_b, out);
}

// Round 4
// 239.559 us; speedup vs baseline: 11.9481x; 1.4197x over previous
//
#include <hip/hip_runtime.h>

#define HH 128
#define WW 256
#define CH 64
#define HWP (HH * WW)   // 32768

typedef __attribute__((ext_vector_type(8))) __bf16 bf16x8;
typedef __attribute__((ext_vector_type(16))) float float16;

__device__ __forceinline__ unsigned short f2bf(float f) {
    unsigned u = __float_as_uint(f);
    u += 0x7fffu + ((u >> 16) & 1u);     // RNE
    return (unsigned short)(u >> 16);
}
__device__ __forceinline__ float bf2f(unsigned short u) {
    return __uint_as_float((unsigned)u << 16);
}

// ---------------------------------------------------------------------------
// Weight prep -> bf16 B-fragment layouts for mfma_f32_32x32x16_bf16.
// frag[((kc*NT + nt)*64 + lane)*8 + j] = W[n][k], n = nt*32+(lane&31),
// k = kc*16 + (lane>>5)*8 + j.
// Segments: [0)rb_w1 [36864)rb_w2 [73728)b1 [77824)b2||b3 [86016)fus [94208)
// ---------------------------------------------------------------------------
__global__ __launch_bounds__(256) void prep_w_k(
    const float* __restrict__ w1, const float* __restrict__ w2,
    const float* __restrict__ b1w, const float* __restrict__ b2w,
    const float* __restrict__ b3w, const float* __restrict__ fusw,
    unsigned short* __restrict__ wB)
{
    int e = blockIdx.x * 256 + threadIdx.x;
    if (e >= 94208) return;
    float val;
    if (e < 73728) {
        const float* w = (e < 36864) ? w1 : w2;
        int t = (e < 36864) ? e : e - 36864;
        int j = t & 7, L = (t >> 3) & 63, nb = (t >> 9) & 1, kc = t >> 10;
        int k  = kc * 16 + (L >> 5) * 8 + j;
        int n  = nb * 32 + (L & 31);
        int kd = k >> 6, ci = k & 63;
        val = w[(n * 64 + ci) * 9 + kd];
    } else {
        int t = e - 73728;
        if (t < 4096) {                       // Q: K=64, NT=2
            int j = t & 7, L = (t >> 3) & 63, i3 = t >> 9;
            int nt = i3 & 1, kc = i3 >> 1;
            int n = nt * 32 + (L & 31), k = kc * 16 + (L >> 5) * 8 + j;
            val = b1w[n * 64 + k];
        } else if (t < 12288) {               // S||R: K=64, NT=4
            t -= 4096;
            int j = t & 7, L = (t >> 3) & 63, i3 = t >> 9;
            int nt = i3 & 3, kc = i3 >> 2;
            int n = nt * 32 + (L & 31), k = kc * 16 + (L >> 5) * 8 + j;
            val = (n < 64) ? b2w[n * 64 + k] : b3w[(n - 64) * 64 + k];
        } else {                              // FUS: K=128, NT=2
            t -= 12288;
            int j = t & 7, L = (t >> 3) & 63, i3 = t >> 9;
            int nt = i3 & 1, kc = i3 >> 1;
            int n = nt * 32 + (L & 31), k = kc * 16 + (L >> 5) * 8 + j;
            val = fusw[n * 128 + k];
        }
    }
    wB[e] = f2bf(val);
}

// ---------------------------------------------------------------------------
// NCHW f32 -> T-layout bf16 (p-major rows of 64 ch).  2048 blocks x 256.
// blocks [0,1024): x_left -> XT[0..], [1024,2048): x_right -> XT[2..].
// ---------------------------------------------------------------------------
__global__ __launch_bounds__(256) void toT_k(
    const float* __restrict__ xl, const float* __restrict__ xr,
    unsigned short* __restrict__ XT)
{
    __shared__ __align__(16) unsigned short sT[64 * 68];
    const int tid = threadIdx.x;
    const int side = blockIdx.x >> 10;
    const int i0   = blockIdx.x & 1023;
    const int gp0  = i0 * 64;
    const int b    = gp0 >> 15;
    const int pofs = gp0 & (HWP - 1);
    const float* in = (side ? xr : xl) + (size_t)b * CH * HWP + pofs;

    for (int i = tid; i < 4096; i += 256) {
        int ci = i >> 6, px = i & 63;
        sT[px * 68 + ci] = f2bf(in[(size_t)ci * HWP + px]);
    }
    __syncthreads();
    const int px = tid >> 2, q = tid & 3;
    unsigned short* op = XT + ((size_t)(side * 2 + b) * HWP + pofs + px) * 64;
#pragma unroll
    for (int r = 0; r < 2; ++r)
        *(uint4*)&op[(q * 2 + r) * 8] = *(uint4*)&sT[px * 68 + (q * 2 + r) * 8];
}

// ---------------------------------------------------------------------------
// conv1: T bf16 in -> lrelu -> T bf16 out.  grid (4,128,4): z = side*2+b.
// ---------------------------------------------------------------------------
__global__ __launch_bounds__(256) void conv1_k(
    const unsigned short* __restrict__ XT, const unsigned short* __restrict__ wB,
    unsigned short* __restrict__ H1T)
{
    __shared__ __align__(16) unsigned short sA[3 * 66 * 68];   // 26928 B

    const int tid = threadIdx.x;
    const int x0  = blockIdx.x * 64;
    const int y   = blockIdx.y;
    const int sb  = blockIdx.z;
    const unsigned short* inT = XT + (size_t)sb * HWP * 64;

    // stage 3x66 halo rows (128 B each) as uint4 copies
    if (tid < 198) {
        int row = tid / 66, col = tid - row * 66;
        int gy = y + row - 1, gx = x0 + col - 1;
        unsigned short* dst = &sA[(row * 66 + col) * 68];
        if ((unsigned)gy < HH && (unsigned)gx < WW) {
            const uint4* src = (const uint4*)&inT[(size_t)(gy * WW + gx) * 64];
#pragma unroll
            for (int j = 0; j < 8; ++j) ((uint4*)dst)[j] = src[j];
        } else {
            uint4 z = make_uint4(0, 0, 0, 0);
#pragma unroll
            for (int j = 0; j < 8; ++j) ((uint4*)dst)[j] = z;
        }
    }
    __syncthreads();

    const int lane = tid & 63, wv = tid >> 6;
    const int mw = wv & 1, nw = wv >> 1;
    const int m = lane & 31, kg = lane >> 5;
    const int px_l = mw * 32 + m;

    float16 acc;
#pragma unroll
    for (int i = 0; i < 16; ++i) acc[i] = 0.f;

#pragma unroll
    for (int kc = 0; kc < 36; ++kc) {
        const int kd = kc >> 2, h = kc & 3;
        const int dy = kd / 3, dx = kd - dy * 3;
        bf16x8 af = *(const bf16x8*)&sA[((dy * 66 + px_l + dx) * 68) + h * 16 + kg * 8];
        bf16x8 bf = *(const bf16x8*)&wB[((kc * 2 + nw) * 64 + lane) * 8];
        acc = __builtin_amdgcn_mfma_f32_32x32x16_bf16(af, bf, acc, 0, 0, 0);
    }

    __syncthreads();
    unsigned short* sCb = sA;                 // [px][ci] stride 68
    const int n = nw * 32 + (lane & 31);
#pragma unroll
    for (int r = 0; r < 16; ++r) {
        int pr = mw * 32 + (r & 3) + 8 * (r >> 2) + 4 * kg;
        float v = acc[r];
        v = v > 0.f ? v : 0.1f * v;
        sCb[pr * 68 + n] = f2bf(v);
    }
    __syncthreads();

    const int px = tid >> 2, q = tid & 3;
    unsigned short* op = H1T + ((size_t)sb * HWP + y * WW + x0 + px) * 64;
#pragma unroll
    for (int r = 0; r < 2; ++r)
        *(uint4*)&op[(q * 2 + r) * 8] = *(uint4*)&sCb[px * 68 + (q * 2 + r) * 8];
}

// ---------------------------------------------------------------------------
// conv2 + residual + fused 1x1 projections.
// side 0 (left):  buf tile -> Q proj -> QT bf16.
// side 1 (right): buf tile -> S,R proj -> ST, RT bf16.
// ---------------------------------------------------------------------------
__global__ __launch_bounds__(256) void conv2_k(
    const unsigned short* __restrict__ H1T, const unsigned short* __restrict__ XT,
    const unsigned short* __restrict__ wB2, const unsigned short* __restrict__ wQ,
    const unsigned short* __restrict__ wSR, const float* __restrict__ b1b,
    const float* __restrict__ b2b, const float* __restrict__ b3b,
    unsigned short* __restrict__ QT, unsigned short* __restrict__ ST,
    unsigned short* __restrict__ RT)
{
    __shared__ __align__(16) unsigned short sA[3 * 66 * 68];

    const int tid = threadIdx.x;
    const int x0  = blockIdx.x * 64;
    const int y   = blockIdx.y;
    const int sb  = blockIdx.z;
    const int side = sb >> 1, b = sb & 1;
    const unsigned short* inT = H1T + (size_t)sb * HWP * 64;

    if (tid < 198) {
        int row = tid / 66, col = tid - row * 66;
        int gy = y + row - 1, gx = x0 + col - 1;
        unsigned short* dst = &sA[(row * 66 + col) * 68];
        if ((unsigned)gy < HH && (unsigned)gx < WW) {
            const uint4* src = (const uint4*)&inT[(size_t)(gy * WW + gx) * 64];
#pragma unroll
            for (int j = 0; j < 8; ++j) ((uint4*)dst)[j] = src[j];
        } else {
            uint4 z = make_uint4(0, 0, 0, 0);
#pragma unroll
            for (int j = 0; j < 8; ++j) ((uint4*)dst)[j] = z;
        }
    }
    __syncthreads();

    const int lane = tid & 63, wv = tid >> 6;
    const int mw = wv & 1, nw = wv >> 1;
    const int m = lane & 31, kg = lane >> 5;
    const int px_l = mw * 32 + m;

    float16 acc;
#pragma unroll
    for (int i = 0; i < 16; ++i) acc[i] = 0.f;

#pragma unroll
    for (int kc = 0; kc < 36; ++kc) {
        const int kd = kc >> 2, h = kc & 3;
        const int dy = kd / 3, dx = kd - dy * 3;
        bf16x8 af = *(const bf16x8*)&sA[((dy * 66 + px_l + dx) * 68) + h * 16 + kg * 8];
        bf16x8 bf = *(const bf16x8*)&wB2[((kc * 2 + nw) * 64 + lane) * 8];
        acc = __builtin_amdgcn_mfma_f32_32x32x16_bf16(af, bf, acc, 0, 0, 0);
    }

    // residual add (bf16 x from XT) -> buf tile bf16 in sCb [px][ci]
    __syncthreads();
    unsigned short* sCb = sA;                          // halves [0, 4352)
    unsigned short* sC2 = sA + 4352;                   // proj output staging
    const int n = nw * 32 + (lane & 31);
    const unsigned short* xres = XT + (size_t)sb * HWP * 64;
#pragma unroll
    for (int r = 0; r < 16; ++r) {
        int pr = mw * 32 + (r & 3) + 8 * (r >> 2) + 4 * kg;
        float xv = bf2f(xres[(size_t)(y * WW + x0 + pr) * 64 + n]);
        sCb[pr * 68 + n] = f2bf(acc[r] + xv);
    }
    __syncthreads();

    // fused projection MFMAs (K=64)
    if (side == 0) {
        float16 a2;
#pragma unroll
        for (int i = 0; i < 16; ++i) a2[i] = 0.f;
#pragma unroll
        for (int kc = 0; kc < 4; ++kc) {
            bf16x8 af = *(const bf16x8*)&sCb[px_l * 68 + kc * 16 + kg * 8];
            bf16x8 bf = *(const bf16x8*)&wQ[((kc * 2 + nw) * 64 + lane) * 8];
            a2 = __builtin_amdgcn_mfma_f32_32x32x16_bf16(af, bf, a2, 0, 0, 0);
        }
        float bv = b1b[n];
#pragma unroll
        for (int r = 0; r < 16; ++r) {
            int pr = mw * 32 + (r & 3) + 8 * (r >> 2) + 4 * kg;
            sC2[pr * 68 + n] = f2bf(a2[r] + bv);
        }
        __syncthreads();
        const int px = tid >> 2, q = tid & 3;
        unsigned short* op = QT + ((size_t)b * HWP + y * WW + x0 + px) * 64;
#pragma unroll
        for (int r = 0; r < 2; ++r)
            *(uint4*)&op[(q * 2 + r) * 8] = *(uint4*)&sC2[px * 68 + (q * 2 + r) * 8];
    } else {
        float16 a2[2];
#pragma unroll
        for (int t = 0; t < 2; ++t)
#pragma unroll
            for (int i = 0; i < 16; ++i) a2[t][i] = 0.f;
#pragma unroll
        for (int kc = 0; kc < 4; ++kc) {
            bf16x8 af = *(const bf16x8*)&sCb[px_l * 68 + kc * 16 + kg * 8];
#pragma unroll
            for (int t = 0; t < 2; ++t) {
                int nt = nw * 2 + t;
                bf16x8 bf = *(const bf16x8*)&wSR[((kc * 4 + nt) * 64 + lane) * 8];
                a2[t] = __builtin_amdgcn_mfma_f32_32x32x16_bf16(af, bf, a2[t], 0, 0, 0);
            }
        }
#pragma unroll
        for (int t = 0; t < 2; ++t) {
            int nn = (nw * 2 + t) * 32 + (lane & 31);
            float bv = (nn < 64) ? b2b[nn] : b3b[nn - 64];
#pragma unroll
            for (int r = 0; r < 16; ++r) {
                int pr = mw * 32 + (r & 3) + 8 * (r >> 2) + 4 * kg;
                sC2[pr * 132 + nn] = f2bf(a2[t][r] + bv);
            }
        }
        __syncthreads();
        const int px = tid >> 2, q = tid & 3;
        const size_t prow = (size_t)b * HWP + y * WW + x0 + px;
        unsigned short* op = ((q < 2) ? ST : RT) + prow * 64 + (q & 1) * 32;
#pragma unroll
        for (int j = 0; j < 4; ++j)
            *(uint4*)&op[j * 8] = *(uint4*)&sC2[px * 132 + q * 32 + j * 8];
    }
}

// ---------------------------------------------------------------------------
// Attention: one wave per pixel, lane = channel.  All operands bf16.
// ---------------------------------------------------------------------------
__global__ __launch_bounds__(256) void attn_k(
    const unsigned short* __restrict__ QT, const unsigned short* __restrict__ ST,
    const unsigned short* __restrict__ RT, const int* __restrict__ xxs,
    const int* __restrict__ yys, unsigned short* __restrict__ bufT,
    float* __restrict__ Mout)
{
    const int lane = threadIdx.x & 63;
    const size_t gp = (size_t)blockIdx.x * 4 + (threadIdx.x >> 6);
    const size_t bbase = (gp >> 15) << 15;

    const float q = bf2f(QT[gp * 64 + lane]);
    const int* xp = xxs + gp * 16;
    const int* yp = yys + gp * 16;
    int idx[16];
#pragma unroll
    for (int k = 0; k < 16; ++k) idx[k] = xp[k] * WW + yp[k];

    float sc[16];
#pragma unroll
    for (int k = 0; k < 16; ++k) {
        float s = bf2f(ST[(bbase + (size_t)idx[k]) * 64 + lane]) * q;
#pragma unroll
        for (int m = 32; m >= 1; m >>= 1) s += __shfl_xor(s, m, 64);
        sc[k] = s;
    }
    float mx = sc[0];
#pragma unroll
    for (int k = 1; k < 16; ++k) mx = fmaxf(mx, sc[k]);
    float e[16];
    float sum = 0.f;
#pragma unroll
    for (int k = 0; k < 16; ++k) { e[k] = __expf(sc[k] - mx); sum += e[k]; }
    const float inv = 1.f / sum;

    float acc = 0.f;
#pragma unroll
    for (int k = 0; k < 16; ++k) {
        const float m = e[k] * inv;
        acc = fmaf(m, bf2f(RT[(bbase + (size_t)idx[k]) * 64 + lane]), acc);
        e[k] = m;
    }
    bufT[gp * 64 + lane] = f2bf(acc);
    if (lane == 0) {
#pragma unroll
        for (int k = 0; k < 16; ++k) Mout[gp * 16 + k] = e[k];
    }
}

// ---------------------------------------------------------------------------
// Fusion 1x1 via MFMA: K=128 (bufT rows + xlT rows, all bf16), NCHW f32 out.
// ---------------------------------------------------------------------------
__global__ __launch_bounds__(256) void fuse_k(
    const unsigned short* __restrict__ bufT, const unsigned short* __restrict__ XT,
    const unsigned short* __restrict__ wfrag, const float* __restrict__ bias,
    float* __restrict__ out)
{
    __shared__ __align__(16) unsigned char smem[64 * 68 * 4];  // 17408 B
    unsigned short* sA = (unsigned short*)smem;   // [px][k] stride 132 halves
    float* sC = (float*)smem;                     // [co][px] stride 68 dwords

    const int tid = threadIdx.x;
    const size_t gp0 = (size_t)blockIdx.x * 64;
    const int b    = (int)(gp0 >> 15);
    const int pofs = (int)(gp0 & (HWP - 1));
    const unsigned short* xlT = XT + ((size_t)b * HWP + pofs) * 64;  // side 0

    for (int i = tid; i < 1024; i += 256) {
        int px = i >> 4, j = i & 15;
        uint4 v;
        if (j < 8) v = *(const uint4*)&bufT[(gp0 + px) * 64 + j * 8];
        else       v = *(const uint4*)&xlT[(size_t)px * 64 + (j - 8) * 8];
        *(uint4*)&sA[px * 132 + ((j < 8) ? j * 8 : 64 + (j - 8) * 8)] = v;
    }
    __syncthreads();

    const int lane = tid & 63, wv = tid >> 6;
    const int mw = wv & 1, nw = wv >> 1;
    const int m = lane & 31, kg = lane >> 5;
    const int px_l = mw * 32 + m;

    float16 acc;
#pragma unroll
    for (int i = 0; i < 16; ++i) acc[i] = 0.f;

#pragma unroll
    for (int kc = 0; kc < 8; ++kc) {
        bf16x8 af = *(const bf16x8*)&sA[px_l * 132 + kc * 16 + kg * 8];
        bf16x8 bf = *(const bf16x8*)&wfrag[((kc * 2 + nw) * 64 + lane) * 8];
        acc = __builtin_amdgcn_mfma_f32_32x32x16_bf16(af, bf, acc, 0, 0, 0);
    }
    __syncthreads();

    const int co_l = nw * 32 + (lane & 31);
#pragma unroll
    for (int r = 0; r < 16; ++r) {
        int pr = mw * 32 + (r & 3) + 8 * (r >> 2) + 4 * kg;
        sC[co_l * 68 + pr] = acc[r];
    }
    __syncthreads();

    const int co = tid >> 2, p0 = (tid & 3) * 16;
    const float bv = bias[co];
    float* op = out + ((size_t)b * CH + co) * HWP + pofs + p0;
#pragma unroll
    for (int q = 0; q < 4; ++q) {
        float4 v = *(float4*)&sC[co * 68 + p0 + q * 4];
        v.x += bv; v.y += bv; v.z += bv; v.w += bv;
        *(float4*)&op[q * 4] = v;
    }
}

// ---------------------------------------------------------------------------
extern "C" void kernel_launch(void* const* d_in, const int* in_sizes, int n_in,
                              void* d_out, int out_size, void* d_ws, size_t ws_size,
                              hipStream_t stream)
{
    const float* x_left  = (const float*)d_in[0];
    const float* x_right = (const float*)d_in[1];
    const int*   xxs     = (const int*)d_in[2];
    const int*   yys     = (const int*)d_in[3];
    const float* rb_w1   = (const float*)d_in[5];
    const float* rb_w2   = (const float*)d_in[6];
    const float* b1_w    = (const float*)d_in[7];
    const float* b1_b    = (const float*)d_in[8];
    const float* b2_w    = (const float*)d_in[9];
    const float* b2_b    = (const float*)d_in[10];
    const float* b3_w    = (const float*)d_in[11];
    const float* b3_b    = (const float*)d_in[12];
    const float* fus_w   = (const float*)d_in[13];
    const float* fus_b   = (const float*)d_in[14];

    float* out  = (float*)d_out;                 // (2,64,128,256)
    float* Mout = out + (size_t)2 * CH * HWP;    // (2,32768,1,16)

    unsigned short* ws2 = (unsigned short*)d_ws;
    unsigned short* XT   = ws2;                  // [side][b][HWP][64]  8388608
    unsigned short* H1T  = ws2 + 8388608;        //                     8388608
    unsigned short* QT   = ws2 + 16777216;       // [b][HWP][64]        4194304
    unsigned short* ST   = ws2 + 20971520;
    unsigned short* RT   = ws2 + 25165824;
    unsigned short* bufT = ws2 + 29360128;
    unsigned short* wB   = ws2 + 33554432;       // 94208 halves

    prep_w_k<<<368, 256, 0, stream>>>(rb_w1, rb_w2, b1_w, b2_w, b3_w, fus_w, wB);
    toT_k<<<2048, 256, 0, stream>>>(x_left, x_right, XT);

    dim3 cgrid(WW / 64, HH, 4), cblk(256);
    conv1_k<<<cgrid, cblk, 0, stream>>>(XT, wB, H1T);
    conv2_k<<<cgrid, cblk, 0, stream>>>(H1T, XT, wB + 36864, wB + 73728,
                                        wB + 77824, b1_b, b2_b, b3_b, QT, ST, RT);

    attn_k<<<16384, 256, 0, stream>>>(QT, ST, RT, xxs, yys, bufT, Mout);
    fuse_k<<<1024, 256, 0, stream>>>(bufT, XT, wB + 86016, fus_b, out);
}

// Round 5
// 201.864 us; speedup vs baseline: 14.1793x; 1.1867x over previous
//
#include <hip/hip_runtime.h>

#define HH 128
#define WW 256
#define CH 64
#define HWP (HH * WW)   // 32768

typedef __attribute__((ext_vector_type(8))) __bf16 bf16x8;
typedef __attribute__((ext_vector_type(16))) float float16;

__device__ __forceinline__ unsigned short f2bf(float f) {
    unsigned u = __float_as_uint(f);
    u += 0x7fffu + ((u >> 16) & 1u);     // RNE
    return (unsigned short)(u >> 16);
}
__device__ __forceinline__ float bf2f(unsigned short u) {
    return __uint_as_float((unsigned)u << 16);
}

// ---------------------------------------------------------------------------
// Weight prep -> bf16 B-fragment layouts for mfma_f32_32x32x16_bf16.
// frag[((kc*NT + nt)*64 + lane)*8 + j] = W[n][k], n = nt*32+(lane&31),
// k = kc*16 + (lane>>5)*8 + j.
// Segments: [0)rb_w1 [36864)rb_w2 [73728)b1 [77824)b2||b3 [86016)fus [94208)
// ---------------------------------------------------------------------------
__global__ __launch_bounds__(256) void prep_w_k(
    const float* __restrict__ w1, const float* __restrict__ w2,
    const float* __restrict__ b1w, const float* __restrict__ b2w,
    const float* __restrict__ b3w, const float* __restrict__ fusw,
    unsigned short* __restrict__ wB)
{
    int e = blockIdx.x * 256 + threadIdx.x;
    if (e >= 94208) return;
    float val;
    if (e < 73728) {
        const float* w = (e < 36864) ? w1 : w2;
        int t = (e < 36864) ? e : e - 36864;
        int j = t & 7, L = (t >> 3) & 63, nb = (t >> 9) & 1, kc = t >> 10;
        int k  = kc * 16 + (L >> 5) * 8 + j;
        int n  = nb * 32 + (L & 31);
        int kd = k >> 6, ci = k & 63;
        val = w[(n * 64 + ci) * 9 + kd];
    } else {
        int t = e - 73728;
        if (t < 4096) {                       // Q: K=64, NT=2
            int j = t & 7, L = (t >> 3) & 63, i3 = t >> 9;
            int nt = i3 & 1, kc = i3 >> 1;
            int n = nt * 32 + (L & 31), k = kc * 16 + (L >> 5) * 8 + j;
            val = b1w[n * 64 + k];
        } else if (t < 12288) {               // S||R: K=64, NT=4
            t -= 4096;
            int j = t & 7, L = (t >> 3) & 63, i3 = t >> 9;
            int nt = i3 & 3, kc = i3 >> 2;
            int n = nt * 32 + (L & 31), k = kc * 16 + (L >> 5) * 8 + j;
            val = (n < 64) ? b2w[n * 64 + k] : b3w[(n - 64) * 64 + k];
        } else {                              // FUS: K=128, NT=2
            t -= 12288;
            int j = t & 7, L = (t >> 3) & 63, i3 = t >> 9;
            int nt = i3 & 1, kc = i3 >> 1;
            int n = nt * 32 + (L & 31), k = kc * 16 + (L >> 5) * 8 + j;
            val = fusw[n * 128 + k];
        }
    }
    wB[e] = f2bf(val);
}

// ---------------------------------------------------------------------------
// NCHW f32 -> T-layout bf16 (p-major rows of 64 ch).  2048 blocks x 256.
// ---------------------------------------------------------------------------
__global__ __launch_bounds__(256) void toT_k(
    const float* __restrict__ xl, const float* __restrict__ xr,
    unsigned short* __restrict__ XT)
{
    __shared__ __align__(16) unsigned short sT[64 * 68];
    const int tid = threadIdx.x;
    const int side = blockIdx.x >> 10;
    const int i0   = blockIdx.x & 1023;
    const int gp0  = i0 * 64;
    const int b    = gp0 >> 15;
    const int pofs = gp0 & (HWP - 1);
    const float* in = (side ? xr : xl) + (size_t)b * CH * HWP + pofs;

    for (int i = tid; i < 4096; i += 256) {
        int ci = i >> 6, px = i & 63;
        sT[px * 68 + ci] = f2bf(in[(size_t)ci * HWP + px]);
    }
    __syncthreads();
    const int px = tid >> 2, q = tid & 3;
    unsigned short* op = XT + ((size_t)(side * 2 + b) * HWP + pofs + px) * 64;
#pragma unroll
    for (int r = 0; r < 2; ++r)
        *(uint4*)&op[(q * 2 + r) * 8] = *(uint4*)&sT[px * 68 + (q * 2 + r) * 8];
}

// halo staging shared by conv1/conv2: 1584 coalesced 16B tasks over 256 thr
__device__ __forceinline__ void stage_halo(
    unsigned short* sA, const unsigned short* inT, int x0, int y, int tid)
{
    for (int i = tid; i < 1584; i += 256) {
        int cell = i >> 3, j = i & 7;
        int row = cell / 66, col = cell - row * 66;
        int gy = y + row - 1, gx = x0 + col - 1;
        uint4 v = make_uint4(0, 0, 0, 0);
        if ((unsigned)gy < HH && (unsigned)gx < WW)
            v = *(const uint4*)&inT[(size_t)(gy * WW + gx) * 64 + j * 8];
        *(uint4*)&sA[(row * 66 + col) * 68 + j * 8] = v;
    }
}

// ---------------------------------------------------------------------------
// conv1: T bf16 in -> lrelu -> T bf16 out.  grid (4,128,4): z = side*2+b.
// ---------------------------------------------------------------------------
__global__ __launch_bounds__(256) void conv1_k(
    const unsigned short* __restrict__ XT, const unsigned short* __restrict__ wB,
    unsigned short* __restrict__ H1T)
{
    __shared__ __align__(16) unsigned short sA[3 * 66 * 68];   // 26928 B

    const int tid = threadIdx.x;
    const int x0  = blockIdx.x * 64;
    const int y   = blockIdx.y;
    const int sb  = blockIdx.z;
    const unsigned short* inT = XT + (size_t)sb * HWP * 64;

    stage_halo(sA, inT, x0, y, tid);
    __syncthreads();

    const int lane = tid & 63, wv = tid >> 6;
    const int mw = wv & 1, nw = wv >> 1;
    const int m = lane & 31, kg = lane >> 5;
    const int px_l = mw * 32 + m;

    float16 acc;
#pragma unroll
    for (int i = 0; i < 16; ++i) acc[i] = 0.f;

#pragma unroll
    for (int kc = 0; kc < 36; ++kc) {
        const int kd = kc >> 2, h = kc & 3;
        const int dy = kd / 3, dx = kd - dy * 3;
        bf16x8 af = *(const bf16x8*)&sA[((dy * 66 + px_l + dx) * 68) + h * 16 + kg * 8];
        bf16x8 bf = *(const bf16x8*)&wB[((kc * 2 + nw) * 64 + lane) * 8];
        acc = __builtin_amdgcn_mfma_f32_32x32x16_bf16(af, bf, acc, 0, 0, 0);
    }

    __syncthreads();
    unsigned short* sCb = sA;                 // [px][ci] stride 68
    const int n = nw * 32 + (lane & 31);
#pragma unroll
    for (int r = 0; r < 16; ++r) {
        int pr = mw * 32 + (r & 3) + 8 * (r >> 2) + 4 * kg;
        float v = acc[r];
        v = v > 0.f ? v : 0.1f * v;
        sCb[pr * 68 + n] = f2bf(v);
    }
    __syncthreads();

    const int px = tid >> 2, q = tid & 3;
    unsigned short* op = H1T + ((size_t)sb * HWP + y * WW + x0 + px) * 64;
#pragma unroll
    for (int r = 0; r < 2; ++r)
        *(uint4*)&op[(q * 2 + r) * 8] = *(uint4*)&sCb[px * 68 + (q * 2 + r) * 8];
}

// ---------------------------------------------------------------------------
// conv2 + residual + fused 1x1 projections.
// side 0 (left):  buf tile -> Q proj -> QT bf16.
// side 1 (right): buf tile -> S,R proj -> ST, RT bf16.
// ---------------------------------------------------------------------------
__global__ __launch_bounds__(256) void conv2_k(
    const unsigned short* __restrict__ H1T, const unsigned short* __restrict__ XT,
    const unsigned short* __restrict__ wB2, const unsigned short* __restrict__ wQ,
    const unsigned short* __restrict__ wSR, const float* __restrict__ b1b,
    const float* __restrict__ b2b, const float* __restrict__ b3b,
    unsigned short* __restrict__ QT, unsigned short* __restrict__ ST,
    unsigned short* __restrict__ RT)
{
    __shared__ __align__(16) unsigned short sA[3 * 66 * 68];

    const int tid = threadIdx.x;
    const int x0  = blockIdx.x * 64;
    const int y   = blockIdx.y;
    const int sb  = blockIdx.z;
    const int side = sb >> 1, b = sb & 1;
    const unsigned short* inT = H1T + (size_t)sb * HWP * 64;

    stage_halo(sA, inT, x0, y, tid);
    __syncthreads();

    const int lane = tid & 63, wv = tid >> 6;
    const int mw = wv & 1, nw = wv >> 1;
    const int m = lane & 31, kg = lane >> 5;
    const int px_l = mw * 32 + m;

    float16 acc;
#pragma unroll
    for (int i = 0; i < 16; ++i) acc[i] = 0.f;

#pragma unroll
    for (int kc = 0; kc < 36; ++kc) {
        const int kd = kc >> 2, h = kc & 3;
        const int dy = kd / 3, dx = kd - dy * 3;
        bf16x8 af = *(const bf16x8*)&sA[((dy * 66 + px_l + dx) * 68) + h * 16 + kg * 8];
        bf16x8 bf = *(const bf16x8*)&wB2[((kc * 2 + nw) * 64 + lane) * 8];
        acc = __builtin_amdgcn_mfma_f32_32x32x16_bf16(af, bf, acc, 0, 0, 0);
    }

    // residual add (bf16 x from XT) -> buf tile bf16 in sCb [px][ci]
    __syncthreads();
    unsigned short* sCb = sA;                          // halves [0, 4352)
    unsigned short* sC2 = sA + 4352;                   // proj output staging
    const int n = nw * 32 + (lane & 31);
    const unsigned short* xres = XT + (size_t)sb * HWP * 64;
#pragma unroll
    for (int r = 0; r < 16; ++r) {
        int pr = mw * 32 + (r & 3) + 8 * (r >> 2) + 4 * kg;
        float xv = bf2f(xres[(size_t)(y * WW + x0 + pr) * 64 + n]);
        sCb[pr * 68 + n] = f2bf(acc[r] + xv);
    }
    __syncthreads();

    // fused projection MFMAs (K=64)
    if (side == 0) {
        float16 a2;
#pragma unroll
        for (int i = 0; i < 16; ++i) a2[i] = 0.f;
#pragma unroll
        for (int kc = 0; kc < 4; ++kc) {
            bf16x8 af = *(const bf16x8*)&sCb[px_l * 68 + kc * 16 + kg * 8];
            bf16x8 bf = *(const bf16x8*)&wQ[((kc * 2 + nw) * 64 + lane) * 8];
            a2 = __builtin_amdgcn_mfma_f32_32x32x16_bf16(af, bf, a2, 0, 0, 0);
        }
        float bv = b1b[n];
#pragma unroll
        for (int r = 0; r < 16; ++r) {
            int pr = mw * 32 + (r & 3) + 8 * (r >> 2) + 4 * kg;
            sC2[pr * 68 + n] = f2bf(a2[r] + bv);
        }
        __syncthreads();
        const int px = tid >> 2, q = tid & 3;
        unsigned short* op = QT + ((size_t)b * HWP + y * WW + x0 + px) * 64;
#pragma unroll
        for (int r = 0; r < 2; ++r)
            *(uint4*)&op[(q * 2 + r) * 8] = *(uint4*)&sC2[px * 68 + (q * 2 + r) * 8];
    } else {
        float16 a2[2];
#pragma unroll
        for (int t = 0; t < 2; ++t)
#pragma unroll
            for (int i = 0; i < 16; ++i) a2[t][i] = 0.f;
#pragma unroll
        for (int kc = 0; kc < 4; ++kc) {
            bf16x8 af = *(const bf16x8*)&sCb[px_l * 68 + kc * 16 + kg * 8];
#pragma unroll
            for (int t = 0; t < 2; ++t) {
                int nt = nw * 2 + t;
                bf16x8 bf = *(const bf16x8*)&wSR[((kc * 4 + nt) * 64 + lane) * 8];
                a2[t] = __builtin_amdgcn_mfma_f32_32x32x16_bf16(af, bf, a2[t], 0, 0, 0);
            }
        }
#pragma unroll
        for (int t = 0; t < 2; ++t) {
            int nn = (nw * 2 + t) * 32 + (lane & 31);
            float bv = (nn < 64) ? b2b[nn] : b3b[nn - 64];
#pragma unroll
            for (int r = 0; r < 16; ++r) {
                int pr = mw * 32 + (r & 3) + 8 * (r >> 2) + 4 * kg;
                sC2[pr * 132 + nn] = f2bf(a2[t][r] + bv);
            }
        }
        __syncthreads();
        const int px = tid >> 2, q = tid & 3;
        const size_t prow = (size_t)b * HWP + y * WW + x0 + px;
        unsigned short* op = ((q < 2) ? ST : RT) + prow * 64 + (q & 1) * 32;
#pragma unroll
        for (int j = 0; j < 4; ++j)
            *(uint4*)&op[j * 8] = *(uint4*)&sC2[px * 132 + q * 32 + j * 8];
    }
}

// ---------------------------------------------------------------------------
// Attention, restructured: one wave per pixel.
// Score phase: lane = cq*16+k (k=key slot, cq=channel quarter). Each lane
// computes a 16-channel partial dot; full dot via 2 shuffles (xor 16,32).
// Softmax over k = lane bits 0-3 (4 butterflies).  M written coalesced by
// lanes 0-15.  V phase: lane = channel, idx/m broadcast via v_readlane.
// ---------------------------------------------------------------------------
__global__ __launch_bounds__(256) void attn_k(
    const unsigned short* __restrict__ QT, const unsigned short* __restrict__ ST,
    const unsigned short* __restrict__ RT, const int* __restrict__ xxs,
    const int* __restrict__ yys, unsigned short* __restrict__ bufT,
    float* __restrict__ Mout)
{
    const int tid  = threadIdx.x;
    const int lane = tid & 63;
    const size_t gp = (size_t)blockIdx.x * 4 + (tid >> 6);
    const size_t bbase = (gp >> 15) << 15;
    const int k  = lane & 15, cq = lane >> 4;

    // per-lane key index
    const int flat = xxs[gp * 16 + k] * WW + yys[gp * 16 + k];

    // 16-channel partial dot: Q[p][cq*16..] . S[flat][cq*16..]
    const unsigned short* srow = ST + (bbase + (size_t)flat) * 64 + cq * 16;
    const unsigned short* qrow = QT + gp * 64 + cq * 16;
    float s = 0.f;
#pragma unroll
    for (int h = 0; h < 2; ++h) {
        uint4 sv = *(const uint4*)(srow + h * 8);
        uint4 qv = *(const uint4*)(qrow + h * 8);
        const unsigned* sa = (const unsigned*)&sv;
        const unsigned* qa = (const unsigned*)&qv;
#pragma unroll
        for (int d = 0; d < 4; ++d) {
            s = fmaf(__uint_as_float(sa[d] << 16),
                     __uint_as_float(qa[d] << 16), s);
            s = fmaf(__uint_as_float(sa[d] & 0xffff0000u),
                     __uint_as_float(qa[d] & 0xffff0000u), s);
        }
    }
    s += __shfl_xor(s, 16, 64);
    s += __shfl_xor(s, 32, 64);            // s = full score[k] on all lanes

    // softmax over the 16 key slots (lane bits 0-3)
    float mx = s;
#pragma unroll
    for (int mm = 1; mm <= 8; mm <<= 1) mx = fmaxf(mx, __shfl_xor(mx, mm, 64));
    const float e = __expf(s - mx);
    float sum = e;
#pragma unroll
    for (int mm = 1; mm <= 8; mm <<= 1) sum += __shfl_xor(sum, mm, 64);
    const float mval = e * (1.f / sum);

    if (lane < 16) Mout[gp * 16 + lane] = mval;

    // V phase: lane = channel; broadcast idx/m from lanes 0-15
    const unsigned short* rbase = RT + bbase * 64;
    float acc = 0.f;
#pragma unroll
    for (int kk = 0; kk < 16; ++kk) {
        int   fi = __builtin_amdgcn_readlane(flat, kk);
        float mk = __uint_as_float(
            __builtin_amdgcn_readlane(__float_as_uint(mval), kk));
        acc = fmaf(mk, bf2f(rbase[(size_t)fi * 64 + lane]), acc);
    }
    bufT[gp * 64 + lane] = f2bf(acc);
}

// ---------------------------------------------------------------------------
// Fusion 1x1 via MFMA: K=128 (bufT rows + xlT rows, all bf16), NCHW f32 out.
// ---------------------------------------------------------------------------
__global__ __launch_bounds__(256) void fuse_k(
    const unsigned short* __restrict__ bufT, const unsigned short* __restrict__ XT,
    const unsigned short* __restrict__ wfrag, const float* __restrict__ bias,
    float* __restrict__ out)
{
    __shared__ __align__(16) unsigned char smem[64 * 68 * 4];  // 17408 B
    unsigned short* sA = (unsigned short*)smem;   // [px][k] stride 132 halves
    float* sC = (float*)smem;                     // [co][px] stride 68 dwords

    const int tid = threadIdx.x;
    const size_t gp0 = (size_t)blockIdx.x * 64;
    const int b    = (int)(gp0 >> 15);
    const int pofs = (int)(gp0 & (HWP - 1));
    const unsigned short* xlT = XT + ((size_t)b * HWP + pofs) * 64;  // side 0

    for (int i = tid; i < 1024; i += 256) {
        int px = i >> 4, j = i & 15;
        uint4 v;
        if (j < 8) v = *(const uint4*)&bufT[(gp0 + px) * 64 + j * 8];
        else       v = *(const uint4*)&xlT[(size_t)px * 64 + (j - 8) * 8];
        *(uint4*)&sA[px * 132 + ((j < 8) ? j * 8 : 64 + (j - 8) * 8)] = v;
    }
    __syncthreads();

    const int lane = tid & 63, wv = tid >> 6;
    const int mw = wv & 1, nw = wv >> 1;
    const int m = lane & 31, kg = lane >> 5;
    const int px_l = mw * 32 + m;

    float16 acc;
#pragma unroll
    for (int i = 0; i < 16; ++i) acc[i] = 0.f;

#pragma unroll
    for (int kc = 0; kc < 8; ++kc) {
        bf16x8 af = *(const bf16x8*)&sA[px_l * 132 + kc * 16 + kg * 8];
        bf16x8 bf = *(const bf16x8*)&wfrag[((kc * 2 + nw) * 64 + lane) * 8];
        acc = __builtin_amdgcn_mfma_f32_32x32x16_bf16(af, bf, acc, 0, 0, 0);
    }
    __syncthreads();

    const int co_l = nw * 32 + (lane & 31);
#pragma unroll
    for (int r = 0; r < 16; ++r) {
        int pr = mw * 32 + (r & 3) + 8 * (r >> 2) + 4 * kg;
        sC[co_l * 68 + pr] = acc[r];
    }
    __syncthreads();

    const int co = tid >> 2, p0 = (tid & 3) * 16;
    const float bv = bias[co];
    float* op = out + ((size_t)b * CH + co) * HWP + pofs + p0;
#pragma unroll
    for (int q = 0; q < 4; ++q) {
        float4 v = *(float4*)&sC[co * 68 + p0 + q * 4];
        v.x += bv; v.y += bv; v.z += bv; v.w += bv;
        *(float4*)&op[q * 4] = v;
    }
}

// ---------------------------------------------------------------------------
extern "C" void kernel_launch(void* const* d_in, const int* in_sizes, int n_in,
                              void* d_out, int out_size, void* d_ws, size_t ws_size,
                              hipStream_t stream)
{
    const float* x_left  = (const float*)d_in[0];
    const float* x_right = (const float*)d_in[1];
    const int*   xxs     = (const int*)d_in[2];
    const int*   yys     = (const int*)d_in[3];
    const float* rb_w1   = (const float*)d_in[5];
    const float* rb_w2   = (const float*)d_in[6];
    const float* b1_w    = (const float*)d_in[7];
    const float* b1_b    = (const float*)d_in[8];
    const float* b2_w    = (const float*)d_in[9];
    const float* b2_b    = (const float*)d_in[10];
    const float* b3_w    = (const float*)d_in[11];
    const float* b3_b    = (const float*)d_in[12];
    const float* fus_w   = (const float*)d_in[13];
    const float* fus_b   = (const float*)d_in[14];

    float* out  = (float*)d_out;                 // (2,64,128,256)
    float* Mout = out + (size_t)2 * CH * HWP;    // (2,32768,1,16)

    unsigned short* ws2 = (unsigned short*)d_ws;
    unsigned short* XT   = ws2;                  // [side][b][HWP][64]  8388608
    unsigned short* H1T  = ws2 + 8388608;
    unsigned short* QT   = ws2 + 16777216;       // [b][HWP][64]        4194304
    unsigned short* ST   = ws2 + 20971520;
    unsigned short* RT   = ws2 + 25165824;
    unsigned short* bufT = ws2 + 29360128;
    unsigned short* wB   = ws2 + 33554432;       // 94208 halves

    prep_w_k<<<368, 256, 0, stream>>>(rb_w1, rb_w2, b1_w, b2_w, b3_w, fus_w, wB);
    toT_k<<<2048, 256, 0, stream>>>(x_left, x_right, XT);

    dim3 cgrid(WW / 64, HH, 4), cblk(256);
    conv1_k<<<cgrid, cblk, 0, stream>>>(XT, wB, H1T);
    conv2_k<<<cgrid, cblk, 0, stream>>>(H1T, XT, wB + 36864, wB + 73728,
                                        wB + 77824, b1_b, b2_b, b3_b, QT, ST, RT);

    attn_k<<<16384, 256, 0, stream>>>(QT, ST, RT, xxs, yys, bufT, Mout);
    fuse_k<<<1024, 256, 0, stream>>>(bufT, XT, wB + 86016, fus_b, out);
}